// Round 6
// baseline (229.283 us; speedup 1.0000x reference)
//
#include <hip/hip_runtime.h>
#include <math.h>

// PerBandSoftAGC: out = x / (clip(EMA_FIR(|x|), eps)^alpha + delta)
// EMA FIR (L=100 taps j=0..99, geometric) via exact sliding recursion:
//   M[t] = q*M[t-1] + w0*|x[t]| - w0*q^100 * |x[t-100]|
// R6: no LDS staging; fp32; chunk-prefix Horner init; nt store. (68us)
// R7: CHUNK=8 halved waves -> 81us. Latency/parallelism bound.
// R8: wave-independent strips (no block barrier) -> 71us, neutral.
// R9: attack the two remaining throughput pipes:
//  (a) tail-drop chunk via cross-lane __shfl: for lane>=25, x4[i4-25] is the
//      own-load of lane-25 in the SAME wave -> 4 ds_bpermute replace a full
//      1KB global load (only lanes 0..24 still load a 400B halo). -33% VMEM
//      instrs, -45% L1/L2 read bytes.
//  (b) per-channel constants {q,alpha,w0,c3,q4,q8} take only 128 values:
//      precompute once into d_ws via a tiny setup kernel -> removes ~8
//      quarter-rate transcendentals per thread from the main kernel.
// Both bitwise-neutral vs R8.

constexpr int T      = 8192;
constexpr int KC_    = 128;
constexpr int BLOCK  = 256;          // 4 independent waves per block
constexpr int WPB    = BLOCK / 64;   // waves per block
constexpr int CHUNK  = 4;
constexpr int WELE   = 64 * CHUNK;   // 256 elements per wave
constexpr int WPR    = T / WELE;     // 32 waves per row
constexpr int NHALO  = 25;           // 100 = 25 chunks of 4
constexpr float EPS_   = 1e-6f;
constexpr float DELTA_ = 0.1f;
constexpr float LOG2E  = 1.4426950408889634f;

typedef float f32x4 __attribute__((ext_vector_type(4)));

__device__ __forceinline__ float fast_sigmoid(float x) {
    const float e = __builtin_amdgcn_exp2f(-x * LOG2E);
    return __builtin_amdgcn_rcpf(1.0f + e);
}

__device__ __forceinline__ float gain_div(float xv, float M, float alpha) {
    const float Mc = fmaxf(M, EPS_);
    // Mc^alpha = exp2(alpha * log2(Mc)); v_log_f32 is log2, v_exp_f32 is exp2
    const float g  = __builtin_amdgcn_exp2f(alpha * __builtin_amdgcn_logf(Mc)) + DELTA_;
    return xv * __builtin_amdgcn_rcpf(g);   // g >= delta = 0.1, rcp safe
}

// ---- one-block setup: per-channel constant table (8 floats per kc) ----
__global__ void agc_setup(const float* __restrict__ alpha_raw,
                          const float* __restrict__ log_s,
                          float* __restrict__ tab)
{
    const int kc = threadIdx.x;            // 128 threads
    const float s     = fast_sigmoid(log_s[kc]);
    const float alpha = 0.5f * fast_sigmoid(alpha_raw[kc]);
    const float q     = 1.0f - s;
    const float lq    = __builtin_amdgcn_logf(q);          // log2(q)
    const float q4    = (q * q) * (q * q);
    const float q8    = q4 * q4;
    const float q100  = __builtin_amdgcn_exp2f(100.0f * lq);
    const float norm  = (1.0f - q100) + 1e-8f;
    const float w0    = s / norm;
    const float c3    = w0 * q100;
    f32x4* t = reinterpret_cast<f32x4*>(tab);
    t[kc * 2]     = f32x4{q, alpha, w0, c3};
    t[kc * 2 + 1] = f32x4{q4, q8, 0.0f, 0.0f};
}

__global__ __launch_bounds__(BLOCK, 8) void agc_kernel(
    const float* __restrict__ x,
    const float* __restrict__ alpha_raw,
    const float* __restrict__ log_s,
    const float* __restrict__ tab,       // may be null -> compute inline
    float* __restrict__ out)
{
    // wave-private prefix regions: 25 halo + 64 own (+pad) each
    __shared__ float Pe[WPB][92];

    const int tid  = threadIdx.x;
    const int lane = tid & 63;
    const int wv   = tid >> 6;
    const int gw   = blockIdx.x * WPB + wv;   // global wave id
    const int row  = gw / WPR;
    const int wrow = gw & (WPR - 1);          // wave index within row
    const int kc   = row & (KC_ - 1);
    const float* __restrict__ xrow = x + (size_t)row * T;
    float* __restrict__ orow       = out + (size_t)row * T;
    const f32x4* __restrict__ x4   = reinterpret_cast<const f32x4*>(xrow);
    f32x4* __restrict__ o4         = reinterpret_cast<f32x4*>(orow);

    const int i4 = (wrow << 6) + lane;        // own float4 index within row

    // ---- own chunk load + (lanes<25 only) halo chunk load ----
    const f32x4 v = x4[i4];
    f32x4 hl = {0.0f, 0.0f, 0.0f, 0.0f};
    const bool halo_lane = (lane < NHALO);
    if (halo_lane && wrow != 0)
        hl = x4[i4 - NHALO];                  // coalesced 25-lane load

    // ---- per-channel scalars (wave-uniform): table or inline fallback ----
    float q, alpha, w0, c3, q4, q8;
    if (tab != nullptr) {
        const f32x4 c0 = reinterpret_cast<const f32x4*>(tab)[kc * 2];
        const f32x4 c1 = reinterpret_cast<const f32x4*>(tab)[kc * 2 + 1];
        q = c0.x; alpha = c0.y; w0 = c0.z; c3 = c0.w; q4 = c1.x; q8 = c1.y;
    } else {
        const float s  = fast_sigmoid(log_s[kc]);
        alpha = 0.5f * fast_sigmoid(alpha_raw[kc]);
        q = 1.0f - s;
        const float lq   = __builtin_amdgcn_logf(q);
        q4 = (q * q) * (q * q);
        q8 = q4 * q4;
        const float q100 = __builtin_amdgcn_exp2f(100.0f * lq);
        const float norm = (1.0f - q100) + 1e-8f;
        w0 = s / norm;
        c3 = w0 * q100;
    }

    // ---- tail-drop chunk: cross-lane pull from lane-25 (same wave) ----
    f32x4 pv;
    pv.x = __shfl(v.x, lane - NHALO, 64);     // wraps for lane<25: overwritten
    pv.y = __shfl(v.y, lane - NHALO, 64);
    pv.z = __shfl(v.z, lane - NHALO, 64);
    pv.w = __shfl(v.w, lane - NHALO, 64);
    if (halo_lane) pv = hl;                   // halo load (or zeros, row start)

    const float a0 = fabsf(v.x),  a1 = fabsf(v.y),  a2 = fabsf(v.z),  a3 = fabsf(v.w);
    const float b0 = fabsf(pv.x), b1 = fabsf(pv.y), b2 = fabsf(pv.z), b3 = fabsf(pv.w);

    // ---- chunk prefixes: P = q^3|e0| + q^2|e1| + q|e2| + |e3| ----
    const float pA = fmaf(q, fmaf(q, fmaf(q, a0, a1), a2), a3);   // own chunk
    const float pB = fmaf(q, fmaf(q, fmaf(q, b0, b1), b2), b3);   // chunk lane-25

    Pe[wv][NHALO + lane] = pA;
    if (halo_lane) Pe[wv][lane] = pB;         // tail prefix IS the halo prefix

    // same-wave DS ordering: LDS ops of one wave execute in order; wait for
    // the writes to land, memory clobber stops compiler reordering the reads.
    asm volatile("s_waitcnt lgkmcnt(0)" ::: "memory");

    // ---- exact init over 25 chunk prefixes (100 taps exactly):
    //      M[t0-1] = w0 * sum_{j=0..24} q^{4(24-j)} * Pe[wv][lane+j]
    //      even/odd split (step q^8) -> two ~12-FMA chains, combined by q^4
    float accE = Pe[wv][lane];
    float accO = Pe[wv][lane + 1];
    #pragma unroll
    for (int j = 2; j <= 24; j += 2) accE = fmaf(accE, q8, Pe[wv][lane + j]);
    #pragma unroll
    for (int j = 3; j <= 23; j += 2) accO = fmaf(accO, q8, Pe[wv][lane + j]);
    float M = w0 * fmaf(q4, accO, accE);      // == M[t0-1], exact

    // ---- 4-step recursion + gain; one coalesced nt float4 store ----
    f32x4 o;
    M = fmaf(q, M, fmaf(w0, a0, -c3 * b0));  o.x = gain_div(v.x, M, alpha);
    M = fmaf(q, M, fmaf(w0, a1, -c3 * b1));  o.y = gain_div(v.y, M, alpha);
    M = fmaf(q, M, fmaf(w0, a2, -c3 * b2));  o.z = gain_div(v.z, M, alpha);
    M = fmaf(q, M, fmaf(w0, a3, -c3 * b3));  o.w = gain_div(v.w, M, alpha);
    __builtin_nontemporal_store(o, &o4[i4]);
}

extern "C" void kernel_launch(void* const* d_in, const int* in_sizes, int n_in,
                              void* d_out, int out_size, void* d_ws, size_t ws_size,
                              hipStream_t stream) {
    const float* x         = (const float*)d_in[0];
    const float* alpha_raw = (const float*)d_in[1];
    const float* log_s     = (const float*)d_in[2];
    float* out             = (float*)d_out;
    const int nrows = in_sizes[0] / T;            // B*KC = 4096
    const int nblocks = nrows * (T / WELE) / WPB; // 32768

    float* tab = nullptr;
    if (d_ws != nullptr && ws_size >= (size_t)(KC_ * 8 * sizeof(float))) {
        tab = (float*)d_ws;
        agc_setup<<<1, KC_, 0, stream>>>(alpha_raw, log_s, tab);
    }
    agc_kernel<<<nblocks, BLOCK, 0, stream>>>(x, alpha_raw, log_s, tab, out);
}

// Round 7
// 228.813 us; speedup vs baseline: 1.0021x; 1.0021x over previous
//
#include <hip/hip_runtime.h>
#include <math.h>

// PerBandSoftAGC: out = x / (clip(EMA_FIR(|x|), eps)^alpha + delta)
// EMA FIR (L=100 taps j=0..99, geometric) via exact sliding recursion:
//   M[t] = q*M[t-1] + w0*|x[t]| - w0*q^100 * |x[t-100]|
// R6: no LDS staging; global tail-drop load; chunk-prefix Horner via LDS. 68us
// R7: half waves -> 81us. R8: wave-private LDS -> 71us. R9: shfl tail -> 73us.
//     R9 lesson: +4 DS ops cost ~5us => wave-wide DS ops ~1.2us each here;
//     R6's Horner carries ~15 DS instrs (unalignable ds_read2) ~= 19us/CU of
//     serialized LDS-pipe time. Conflict-free != free.
// R10: ZERO DS instructions. Window sum via DPP weighted wave scan (VALU):
//   c_l = own chunk prefix (pA), c_{l-25} = tail chunk prefix (pB, from the
//   tail-drop load). W_{l+1} = q4*W_l + d_l with d_l = pA - q100*pB solves to
//   W_l = q4^l * H + sum_{i<l} q4^{l-1-i} d_i.
//   Exclusive weighted sum: shift-up-1 (row_shr:1 + bcast patches) then
//   6-step Kogge-Stone scan with factors q4^{1,2,4,8} and per-lane powers at
//   the row_bcast:15/31 crossings. H = halo total via one DPP prefix-sum +
//   readlane(63). No LDS array, no fence, no bpermute.

constexpr int T      = 8192;
constexpr int KC_    = 128;
constexpr int BLOCK  = 256;          // 4 independent waves per block
constexpr int WPB    = BLOCK / 64;
constexpr int WELE   = 256;          // 64 lanes x 4 elements per wave
constexpr int WPR    = T / WELE;     // 32 waves per row
constexpr int NHALO  = 25;           // 100 = 25 chunks of 4
constexpr float EPS_   = 1e-6f;
constexpr float DELTA_ = 0.1f;
constexpr float LOG2E  = 1.4426950408889634f;

typedef float f32x4 __attribute__((ext_vector_type(4)));

// DPP move with old=0: unselected rows / OOB-source lanes read 0.
// ctrl: row_shr:n = 0x110|n; row_bcast:15 = 0x142; row_bcast:31 = 0x143.
template<int CTRL, int ROWM>
__device__ __forceinline__ float dpp0(float v) {
    return __builtin_bit_cast(float,
        __builtin_amdgcn_update_dpp(0, __builtin_bit_cast(int, v),
                                    CTRL, ROWM, 0xf, true));
}

__device__ __forceinline__ float fast_sigmoid(float x) {
    const float e = __builtin_amdgcn_exp2f(-x * LOG2E);
    return __builtin_amdgcn_rcpf(1.0f + e);
}

__device__ __forceinline__ float gain_div(float xv, float M, float alpha) {
    const float Mc = fmaxf(M, EPS_);
    // Mc^alpha = exp2(alpha * log2(Mc)); v_log_f32 is log2, v_exp_f32 is exp2
    const float g  = __builtin_amdgcn_exp2f(alpha * __builtin_amdgcn_logf(Mc)) + DELTA_;
    return xv * __builtin_amdgcn_rcpf(g);   // g >= delta = 0.1, rcp safe
}

// ---- one-block setup: per-channel constant table (8 floats per kc) ----
__global__ void agc_setup(const float* __restrict__ alpha_raw,
                          const float* __restrict__ log_s,
                          float* __restrict__ tab)
{
    const int kc = threadIdx.x;            // 128 threads
    const float s     = fast_sigmoid(log_s[kc]);
    const float alpha = 0.5f * fast_sigmoid(alpha_raw[kc]);
    const float q     = 1.0f - s;
    const float lq    = __builtin_amdgcn_logf(q);          // log2(q)
    const float lq4   = 4.0f * lq;                         // log2(q^4)
    const float q4    = __builtin_amdgcn_exp2f(lq4);
    const float q100  = __builtin_amdgcn_exp2f(100.0f * lq);
    const float norm  = (1.0f - q100) + 1e-8f;
    const float w0    = s / norm;
    const float c3    = w0 * q100;
    f32x4* t = reinterpret_cast<f32x4*>(tab);
    t[kc * 2]     = f32x4{q, alpha, w0, c3};
    t[kc * 2 + 1] = f32x4{q4, q100, lq4, 0.0f};
}

__global__ __launch_bounds__(BLOCK, 8) void agc_kernel(
    const float* __restrict__ x,
    const float* __restrict__ alpha_raw,
    const float* __restrict__ log_s,
    const float* __restrict__ tab,       // may be null -> compute inline
    float* __restrict__ out)
{
    const int tid  = threadIdx.x;
    const int lane = tid & 63;
    const int wv   = tid >> 6;
    const int gw   = blockIdx.x * WPB + wv;   // global wave id
    const int row  = gw / WPR;
    const int wrow = gw & (WPR - 1);          // wave index within row
    const int kc   = row & (KC_ - 1);
    const float* __restrict__ xrow = x + (size_t)row * T;
    float* __restrict__ orow       = out + (size_t)row * T;
    const f32x4* __restrict__ x4   = reinterpret_cast<const f32x4*>(xrow);
    f32x4* __restrict__ o4         = reinterpret_cast<f32x4*>(orow);

    const int i4 = (wrow << 6) + lane;        // own float4 index within row

    // ---- two coalesced float4 loads: own chunk + tail-drop chunk ----
    const f32x4 v = x4[i4];
    f32x4 pv = {0.0f, 0.0f, 0.0f, 0.0f};
    if (wrow != 0 || lane >= NHALO)           // zeros before row start
        pv = x4[i4 - NHALO];

    // ---- per-channel scalars (wave-uniform): table or inline fallback ----
    float q, alpha, w0, c3, q4, q100, lq4;
    if (tab != nullptr) {
        const f32x4 c0 = reinterpret_cast<const f32x4*>(tab)[kc * 2];
        const f32x4 c1 = reinterpret_cast<const f32x4*>(tab)[kc * 2 + 1];
        q = c0.x; alpha = c0.y; w0 = c0.z; c3 = c0.w;
        q4 = c1.x; q100 = c1.y; lq4 = c1.z;
    } else {
        const float s  = fast_sigmoid(log_s[kc]);
        alpha = 0.5f * fast_sigmoid(alpha_raw[kc]);
        q = 1.0f - s;
        const float lq = __builtin_amdgcn_logf(q);
        lq4  = 4.0f * lq;
        q4   = __builtin_amdgcn_exp2f(lq4);
        q100 = __builtin_amdgcn_exp2f(100.0f * lq);
        const float norm = (1.0f - q100) + 1e-8f;
        w0 = s / norm;
        c3 = w0 * q100;
    }

    const float a0 = fabsf(v.x),  a1 = fabsf(v.y),  a2 = fabsf(v.z),  a3 = fabsf(v.w);
    const float b0 = fabsf(pv.x), b1 = fabsf(pv.y), b2 = fabsf(pv.z), b3 = fabsf(pv.w);

    // ---- chunk prefixes: P = q^3|e0| + q^2|e1| + q|e2| + |e3| ----
    const float pA = fmaf(q, fmaf(q, fmaf(q, a0, a1), a2), a3);   // chunk l
    const float pB = fmaf(q, fmaf(q, fmaf(q, b0, b1), b2), b3);   // chunk l-25

    // ---- d_l = pA - q100 * pB ; shift up by 1 lane (e_l = d_{l-1}) ----
    const float d  = fmaf(-q100, pB, pA);
    float e        = dpp0<0x111, 0xf>(d);     // within-row shr:1, zero-fill
    const float dA = dpp0<0x142, 0xa>(d);     // lanes16-31<-d15, 48-63<-d47
    const float dB = dpp0<0x143, 0xc>(d);     // lanes32-63<-d31
    if ((lane & 15) == 0 && lane != 0)        // patch row crossings 16/32/48
        e = (lane == 32) ? dB : dA;

    // ---- weighted inclusive scan of e: Ex_l = sum_{i<=l} q4^{l-i} e_i
    //      == exclusive window accumulator sum_{i<l} q4^{l-1-i} d_i ----
    const float q4_2 = q4 * q4, q4_4 = q4_2 * q4_2, q4_8 = q4_4 * q4_4;
    const float lf   = (float)lane;
    const float l31  = (float)(lane & 31);
    float Ex = e;
    Ex = fmaf(q4,   dpp0<0x111, 0xf>(Ex), Ex);
    Ex = fmaf(q4_2, dpp0<0x112, 0xf>(Ex), Ex);
    Ex = fmaf(q4_4, dpp0<0x114, 0xf>(Ex), Ex);
    Ex = fmaf(q4_8, dpp0<0x118, 0xf>(Ex), Ex);
    const float f15 = __builtin_amdgcn_exp2f(fmaxf(l31 - 15.0f, 0.0f) * lq4);
    Ex = fmaf(f15, dpp0<0x142, 0xa>(Ex), Ex);   // cross 16-lane rows
    const float f31 = __builtin_amdgcn_exp2f(fmaxf(lf - 31.0f, 0.0f) * lq4);
    Ex = fmaf(f31, dpp0<0x143, 0xc>(Ex), Ex);   // cross 32-lane halves

    // ---- halo total H = sum_{i=0..24} q4^{24-i} pB_i : DPP prefix-sum ----
    const float wt = __builtin_amdgcn_exp2f(fmaxf(24.0f - lf, 0.0f) * lq4);
    float Hs = (lane < NHALO) ? pB * wt : 0.0f;
    Hs += dpp0<0x111, 0xf>(Hs);
    Hs += dpp0<0x112, 0xf>(Hs);
    Hs += dpp0<0x114, 0xf>(Hs);
    Hs += dpp0<0x118, 0xf>(Hs);
    Hs += dpp0<0x142, 0xa>(Hs);
    Hs += dpp0<0x143, 0xc>(Hs);
    const float H = __builtin_bit_cast(float,
        __builtin_amdgcn_readlane(__builtin_bit_cast(int, Hs), 63));

    // ---- M[t0-1] = w0 * ( q4^lane * H + Ex ), exact 100-tap window ----
    const float qp = __builtin_amdgcn_exp2f(lf * lq4);
    float M = w0 * fmaf(qp, H, Ex);

    // ---- 4-step recursion + gain; one coalesced nt float4 store ----
    f32x4 o;
    M = fmaf(q, M, fmaf(w0, a0, -c3 * b0));  o.x = gain_div(v.x, M, alpha);
    M = fmaf(q, M, fmaf(w0, a1, -c3 * b1));  o.y = gain_div(v.y, M, alpha);
    M = fmaf(q, M, fmaf(w0, a2, -c3 * b2));  o.z = gain_div(v.z, M, alpha);
    M = fmaf(q, M, fmaf(w0, a3, -c3 * b3));  o.w = gain_div(v.w, M, alpha);
    __builtin_nontemporal_store(o, &o4[i4]);
}

extern "C" void kernel_launch(void* const* d_in, const int* in_sizes, int n_in,
                              void* d_out, int out_size, void* d_ws, size_t ws_size,
                              hipStream_t stream) {
    const float* x         = (const float*)d_in[0];
    const float* alpha_raw = (const float*)d_in[1];
    const float* log_s     = (const float*)d_in[2];
    float* out             = (float*)d_out;
    const int nrows = in_sizes[0] / T;            // B*KC = 4096
    const int nblocks = nrows * WPR / WPB;        // 32768

    float* tab = nullptr;
    if (d_ws != nullptr && ws_size >= (size_t)(KC_ * 8 * sizeof(float))) {
        tab = (float*)d_ws;
        agc_setup<<<1, KC_, 0, stream>>>(alpha_raw, log_s, tab);
    }
    agc_kernel<<<nblocks, BLOCK, 0, stream>>>(x, alpha_raw, log_s, tab, out);
}